// Round 1
// baseline (26.084 us; speedup 1.0000x reference)
//
#include <hip/hip_runtime.h>
#include <hip/hip_bf16.h>
#include <math.h>

// Problem constants (mirror the reference module-level config)
#define IMG_H     256
#define IMG_W     256
#define BLK_H     8
#define BLK_W     8
#define N_BLOCKS  512
#define TILES     1024   // (256/8)*(256/8)
#define BATCH     32
#define GRID_W    32     // tiles per image row

// One 64-lane wave per (b, l) row: argmax over 512 logits+gumbel, then
// scatter the winning 8x8 block into the output image.
__global__ __launch_bounds__(256) void ImageReconstruction_55825984913931_kernel(
    const int*   __restrict__ frame_idxs,   // [BATCH]
    const float* __restrict__ sequence,     // [N_SEQ, TILES, N_BLOCKS]
    const float* __restrict__ blocks,       // [N_BLOCKS, 8, 8]
    const float* __restrict__ gumbel,       // [BATCH, TILES, N_BLOCKS]
    float*       __restrict__ out)          // [BATCH, 1, 256, 256]
{
    const int wave = threadIdx.x >> 6;           // 4 waves per block
    const int lane = threadIdx.x & 63;
    const int row  = blockIdx.x * 4 + wave;      // [0, BATCH*TILES)
    const int b    = row >> 10;                  // / TILES
    const int l    = row & (TILES - 1);

    const int fi = frame_idxs[b];
    const float* __restrict__ seq_row = sequence + ((size_t)fi * TILES + l) * N_BLOCKS;
    const float* __restrict__ gum_row = gumbel   + ((size_t)b  * TILES + l) * N_BLOCKS;

    float best = -INFINITY;
    int   bidx = 0x7fffffff;

    // 512 elements = 2 chunks x 64 lanes x float4; coalesced 16B/lane loads.
    #pragma unroll
    for (int c = 0; c < 2; ++c) {
        const int base = c * 256 + lane * 4;
        const float4 s = *reinterpret_cast<const float4*>(seq_row + base);
        const float4 g = *reinterpret_cast<const float4*>(gum_row + base);
        const float v[4] = { s.x + g.x, s.y + g.y, s.z + g.z, s.w + g.w };
        #pragma unroll
        for (int j = 0; j < 4; ++j) {
            // increasing index order + strict '>' keeps the earliest max
            if (v[j] > best) { best = v[j]; bidx = base + j; }
        }
    }

    // Butterfly reduce across the 64-lane wave; tie-break: lowest index.
    #pragma unroll
    for (int off = 32; off >= 1; off >>= 1) {
        const float ov = __shfl_xor(best, off, 64);
        const int   oi = __shfl_xor(bidx, off, 64);
        if (ov > best || (ov == best && oi < bidx)) { best = ov; bidx = oi; }
    }

    // Scatter blocks[bidx] (64 f32, L2-resident: 128 KB total) into the image.
    const float val = blocks[bidx * (BLK_H * BLK_W) + lane];
    const int ti = l >> 5;            // tile row
    const int tj = l & (GRID_W - 1);  // tile col
    const int r  = ti * BLK_H + (lane >> 3);
    const int cc = tj * BLK_W + (lane & 7);
    out[(size_t)b * (IMG_H * IMG_W) + r * IMG_W + cc] = val;
}

extern "C" void kernel_launch(void* const* d_in, const int* in_sizes, int n_in,
                              void* d_out, int out_size, void* d_ws, size_t ws_size,
                              hipStream_t stream) {
    const int*   frame_idxs = (const int*)  d_in[0];
    const float* sequence   = (const float*)d_in[1];
    const float* blocks     = (const float*)d_in[2];
    const float* gumbel     = (const float*)d_in[3];
    float*       out        = (float*)      d_out;

    const int rows = BATCH * TILES;              // 32768 waves
    const int grid = rows / 4;                   // 4 waves (256 threads) per block
    ImageReconstruction_55825984913931_kernel<<<grid, 256, 0, stream>>>(
        frame_idxs, sequence, blocks, gumbel, out);
}